// Round 13
// baseline (927.066 us; speedup 1.0000x reference)
//
#include <hip/hip_runtime.h>
#include <hip/hip_bf16.h>

typedef unsigned int uint;
typedef unsigned short ushort;
typedef unsigned char uchar;
typedef __attribute__((ext_vector_type(8))) short short8;
typedef __attribute__((ext_vector_type(4))) float f32x4;
typedef __attribute__((ext_vector_type(4))) uint u32x4;

__device__ __forceinline__ float bf2f(ushort u) {
    union { uint i; float f; } v; v.i = ((uint)u) << 16; return v.f;
}
__device__ __forceinline__ ushort f2bf(float f) {
    union { float f; uint i; } v; v.f = f;
    uint x = v.i;
    uint r = (x + 0x7FFFu + ((x >> 16) & 1u)) >> 16;
    return (ushort)r;
}
// fp8 e4m3 encode via HW cvt
__device__ __forceinline__ uchar f2q(float f) {
    return (uchar)(__builtin_amdgcn_cvt_pk_fp8_f32(f, 0.f, 0, false) & 0xFF);
}
// decode 4 fp8 from a word (literal selectors required)
__device__ __forceinline__ void q2f4(uint w, float* o) {
    o[0] = __builtin_amdgcn_cvt_f32_fp8(w, 0);
    o[1] = __builtin_amdgcn_cvt_f32_fp8(w, 1);
    o[2] = __builtin_amdgcn_cvt_f32_fp8(w, 2);
    o[3] = __builtin_amdgcn_cvt_f32_fp8(w, 3);
}

// ---------------- init: all zeroing in one launch ----------------

__global__ void k_init(int* __restrict__ deg, int* __restrict__ cursor,
                       int* __restrict__ hist, int* __restrict__ cursB,
                       float* __restrict__ pooled,
                       uchar* __restrict__ h1qN, uchar* __restrict__ h2qN, int n) {
    int i = blockIdx.x * 256 + threadIdx.x;
    if (i < n) { deg[i] = 0; cursor[i] = 0; }
    if (i < 64) { hist[i] = 0; cursB[i] = 0; }
    if (i < 128) pooled[i] = 0.f;
    if (i < 32) {
        reinterpret_cast<uint*>(h1qN)[i] = 0;      // zero row N of fp8 tables
        reinterpret_cast<uint*>(h2qN)[i] = 0;
    }
}

// ---------------- graph prep ----------------
// Binned by dst range (bin = blockIdx & 7): each 64B line of deg/cursor/csr
// is written by one XCD only -> no cross-XCD partial-line writeback (R5 fix).

__global__ void k_degree(const int* __restrict__ dst, int* __restrict__ deg,
                         int e, int n) {
    int bin = blockIdx.x & 7;
    int sub = blockIdx.x >> 3;
    int nsub = gridDim.x >> 3;
    int q = (n + 7) >> 3;
    int lo = bin * q, hi = min(n, lo + q);
    for (int i = sub * 256 + threadIdx.x; i < e; i += nsub * 256) {
        int d = dst[i];
        if (d >= lo && d < hi) atomicAdd(&deg[d], 1);
    }
}

__global__ void k_dinv(const int* __restrict__ deg, float* __restrict__ dinv, int n) {
    int i = blockIdx.x * 256 + threadIdx.x;
    if (i < n) dinv[i] = rsqrtf((float)deg[i] + 1.0f);  // +1 self-loop
}

// 3-kernel exclusive scan of edge-degree -> offsets. chunk = 1024/block.
__global__ void k_scan_a(const int* __restrict__ deg, int* __restrict__ bsum, int n) {
    __shared__ int sd[256];
    int t = threadIdx.x;
    int base = blockIdx.x * 1024 + t * 4;
    int s = 0;
#pragma unroll
    for (int j = 0; j < 4; ++j) { int idx = base + j; if (idx < n) s += deg[idx]; }
    sd[t] = s; __syncthreads();
    for (int off = 1; off < 256; off <<= 1) {
        int v = (t >= off) ? sd[t - off] : 0;
        __syncthreads();
        sd[t] += v;
        __syncthreads();
    }
    if (t == 255) bsum[blockIdx.x] = sd[255];
}

__global__ void k_scan_b(const int* __restrict__ bsum, int* __restrict__ boff, int nb) {
    __shared__ int sd[256];
    int t = threadIdx.x;
    int v0 = (t < nb) ? bsum[t] : 0;
    sd[t] = v0; __syncthreads();
    for (int off = 1; off < 256; off <<= 1) {
        int v = (t >= off) ? sd[t - off] : 0;
        __syncthreads();
        sd[t] += v;
        __syncthreads();
    }
    if (t < nb) boff[t] = sd[t] - v0;  // exclusive
}

__global__ void k_scan_c(const int* __restrict__ deg, const int* __restrict__ boff,
                         int* __restrict__ offs, int n) {
    __shared__ int sd[256];
    int t = threadIdx.x;
    int base = blockIdx.x * 1024 + t * 4;
    int vals[4]; int s = 0;
#pragma unroll
    for (int j = 0; j < 4; ++j) {
        int idx = base + j;
        vals[j] = (idx < n) ? deg[idx] : 0;
        s += vals[j];
    }
    sd[t] = s; __syncthreads();
    for (int off = 1; off < 256; off <<= 1) {
        int v = (t >= off) ? sd[t - off] : 0;
        __syncthreads();
        sd[t] += v;
        __syncthreads();
    }
    int run = boff[blockIdx.x] + (sd[t] - s);
#pragma unroll
    for (int j = 0; j < 4; ++j) {
        int idx = base + j;
        if (idx < n) { offs[idx] = run; run += vals[j]; }
    }
}

__global__ void k_fill(const int* __restrict__ src, const int* __restrict__ dst,
                       const int* __restrict__ offs, int* __restrict__ cursor,
                       int* __restrict__ csr, int e, int n) {
    int bin = blockIdx.x & 7;
    int sub = blockIdx.x >> 3;
    int nsub = gridDim.x >> 3;
    int q = (n + 7) >> 3;
    int lo = bin * q, hi = min(n, lo + q);
    for (int i = sub * 256 + threadIdx.x; i < e; i += nsub * 256) {
        int d = dst[i];
        if (d >= lo && d < hi) {
            int p = offs[d] + atomicAdd(&cursor[d], 1);
            csr[p] = src[i];
        }
    }
}

// ---------------- counting sort of nodes by degree (key clamped to 63) ------
// Removes wave divergence in aggs: the 8 groups of a wave get equal-degree
// nodes -> equal batch counts -> no masked-off gather slots (R11 post-mortem:
// ~30-45% of wave gather slots were wasted on max-degree straggler groups).
// Three DISTINCT buffers: hist (counts), base (scan out), cursB (zeroed) —
// R12 crashed by aliasing cursors onto the un-zeroed hist.

__global__ void k_hist(const int* __restrict__ deg, int* __restrict__ hist, int n) {
    int i = blockIdx.x * 256 + threadIdx.x;
    if (i < n) atomicAdd(&hist[min(deg[i], 63)], 1);
}

__global__ void k_sortscan(const int* __restrict__ hist, int* __restrict__ base) {
    __shared__ int sd[64];
    int t = threadIdx.x;
    int v0 = hist[t];
    sd[t] = v0; __syncthreads();
    for (int off = 1; off < 64; off <<= 1) {
        int v = (t >= off) ? sd[t - off] : 0;
        __syncthreads();
        sd[t] += v;
        __syncthreads();
    }
    base[t] = sd[t] - v0;  // exclusive
}

__global__ void k_scatter(const int* __restrict__ deg, const int* __restrict__ base,
                          int* __restrict__ cursB, int* __restrict__ order, int n) {
    int i = blockIdx.x * 256 + threadIdx.x;
    if (i < n) {
        int b = min(deg[i], 63);
        int pos = base[b] + atomicAdd(&cursB[b], 1);
        order[pos] = i;
    }
}

// ---------------- GEMM1: h1q = fp8((x@W1)*dinv), xfc = bf16(relu(x@We+be)) ----------------

__global__ __launch_bounds__(512) void k_gemm1(
    const float* __restrict__ x, const float* __restrict__ W1, const float* __restrict__ We,
    const float* __restrict__ be, const float* __restrict__ dinv,
    uchar* __restrict__ h1q, ushort* __restrict__ xfc, int n)
{
    __shared__ __align__(16) ushort Bt[256][72];  // [col][k_local], pad 72 for banks
    int tid = threadIdx.x;
    int w = tid >> 6, lane = tid & 63;
    int ln15 = lane & 15, g = lane >> 4;
    int rowBase = blockIdx.x * 128 + w * 16;
    int r = rowBase + ln15;
    bool valid = r < n;

    short8 a[4];
#pragma unroll
    for (int ks = 0; ks < 4; ++ks) {
        float4 f0 = make_float4(0.f, 0.f, 0.f, 0.f), f1 = f0;
        if (valid) {
            const float* p = x + (size_t)r * 128 + ks * 32 + g * 8;
            f0 = *reinterpret_cast<const float4*>(p);
            f1 = *reinterpret_cast<const float4*>(p + 4);
        }
        short8 v;
        v[0] = (short)f2bf(f0.x); v[1] = (short)f2bf(f0.y);
        v[2] = (short)f2bf(f0.z); v[3] = (short)f2bf(f0.w);
        v[4] = (short)f2bf(f1.x); v[5] = (short)f2bf(f1.y);
        v[6] = (short)f2bf(f1.z); v[7] = (short)f2bf(f1.w);
        a[ks] = v;
    }

    f32x4 acc[16];
#pragma unroll
    for (int i = 0; i < 16; ++i) acc[i] = (f32x4){0.f, 0.f, 0.f, 0.f};

    for (int s = 0; s < 2; ++s) {
        for (int i = tid; i < 8192; i += 512) {
            int kl = i >> 7, j = i & 127;
            int kg = s * 64 + kl;
            Bt[j][kl]       = f2bf(W1[kg * 128 + j]);
            Bt[128 + j][kl] = f2bf(We[kg * 128 + j]);
        }
        __syncthreads();
#pragma unroll
        for (int t2 = 0; t2 < 2; ++t2) {
            short8 af = a[s * 2 + t2];
#pragma unroll
            for (int jf = 0; jf < 16; ++jf) {
                short8 bf = *reinterpret_cast<const short8*>(&Bt[jf * 16 + ln15][t2 * 32 + g * 8]);
                acc[jf] = __builtin_amdgcn_mfma_f32_16x16x32_bf16(af, bf, acc[jf], 0, 0, 0);
            }
        }
        __syncthreads();
    }

    float dv[4];
#pragma unroll
    for (int q = 0; q < 4; ++q) {
        int rr = rowBase + g * 4 + q;
        dv[q] = (rr < n) ? dinv[rr] : 0.f;
    }

    // D layout: col = lane&15, row = (lane>>4)*4 + q
#pragma unroll
    for (int jf = 0; jf < 16; ++jf) {
        int col = jf * 16 + ln15;
#pragma unroll
        for (int q = 0; q < 4; ++q) {
            int rr = rowBase + g * 4 + q;
            if (rr < n) {
                float v = acc[jf][q];
                if (col < 128) {
                    h1q[(size_t)rr * 128 + col] = f2q(v * dv[q]);
                } else {
                    float vv = fmaxf(v + be[col - 128], 0.f);
                    xfc[(size_t)rr * 128 + (col - 128)] = f2bf(vv);
                }
            }
        }
    }
}

// ---------------- GEMM2: h2q = fp8((h@W2)*dinv) (bf16 in) ----------------

__global__ __launch_bounds__(512) void k_gemm2(
    const ushort* __restrict__ h, const float* __restrict__ W2, const float* __restrict__ dinv,
    uchar* __restrict__ h2q, int n)
{
    __shared__ __align__(16) ushort Bt[128][72];
    int tid = threadIdx.x;
    int w = tid >> 6, lane = tid & 63;
    int ln15 = lane & 15, g = lane >> 4;
    int rowBase = blockIdx.x * 128 + w * 16;
    int r = rowBase + ln15;
    bool valid = r < n;

    short8 a[4];
#pragma unroll
    for (int ks = 0; ks < 4; ++ks) {
        short8 v = (short8){0,0,0,0,0,0,0,0};
        if (valid) v = *reinterpret_cast<const short8*>(h + (size_t)r * 128 + ks * 32 + g * 8);
        a[ks] = v;
    }

    f32x4 acc[8];
#pragma unroll
    for (int i = 0; i < 8; ++i) acc[i] = (f32x4){0.f, 0.f, 0.f, 0.f};

    for (int s = 0; s < 2; ++s) {
        for (int i = tid; i < 8192; i += 512) {
            int kl = i >> 7, j = i & 127;
            Bt[j][kl] = f2bf(W2[(s * 64 + kl) * 128 + j]);
        }
        __syncthreads();
#pragma unroll
        for (int t2 = 0; t2 < 2; ++t2) {
            short8 af = a[s * 2 + t2];
#pragma unroll
            for (int jf = 0; jf < 8; ++jf) {
                short8 bf = *reinterpret_cast<const short8*>(&Bt[jf * 16 + ln15][t2 * 32 + g * 8]);
                acc[jf] = __builtin_amdgcn_mfma_f32_16x16x32_bf16(af, bf, acc[jf], 0, 0, 0);
            }
        }
        __syncthreads();
    }

    float dv[4];
#pragma unroll
    for (int q = 0; q < 4; ++q) {
        int rr = rowBase + g * 4 + q;
        dv[q] = (rr < n) ? dinv[rr] : 0.f;
    }

#pragma unroll
    for (int jf = 0; jf < 8; ++jf) {
        int col = jf * 16 + ln15;
#pragma unroll
        for (int q = 0; q < 4; ++q) {
            int rr = rowBase + g * 4 + q;
            if (rr < n) h2q[(size_t)rr * 128 + col] = f2q(acc[jf][q] * dv[q]);
        }
    }
}

// ---------------- aggregation 1 (degree-sorted order) ----------------
// h_i = relu(dinv_i*(sum_{s in N(i)} h1q[s] + h1q[i]) + b1) + xfc_i   (bf16 out)
// 8-lane group per node (best measured shape, R5: 8 rows x 16B per gather
// instruction). Nodes processed in degree-sorted order -> all 8 groups of a
// wave run the same batch count (no divergence waste). Tail edges clamp to
// zero-row n. csr padded +64.

__global__ __launch_bounds__(256) void k_agg1(
    const int* __restrict__ csr, const int* __restrict__ offs, const int* __restrict__ degE,
    const float* __restrict__ dinv, const uchar* __restrict__ h1q, const ushort* __restrict__ xfc,
    const float* __restrict__ b1, ushort* __restrict__ h, const int* __restrict__ order, int n)
{
    int t = threadIdx.x;
    int g = t >> 3, li = t & 7;
    int j = blockIdx.x * 32 + g;
    if (j >= n) return;
    int node = order[j];
    int off = offs[node], cnt = degE[node];
    float di = dinv[node];
    int c0 = li * 16;
    const uchar* tbl = h1q + c0;
    float acc[16];
#pragma unroll
    for (int e = 0; e < 16; ++e) acc[e] = 0.f;

    for (int base = 0; base < cnt; base += 8) {
        u32x4 u[8];
#pragma unroll
        for (int q = 0; q < 8; ++q) {
            int s = csr[off + base + q];            // group-uniform
            int id = (base + q < cnt) ? s : n;      // zero row for tail
            u[q] = *reinterpret_cast<const u32x4*>(tbl + (size_t)id * 128);
        }
#pragma unroll
        for (int q = 0; q < 8; ++q) {
            float d4[4];
            q2f4(u[q][0], d4); acc[0] += d4[0]; acc[1] += d4[1]; acc[2] += d4[2]; acc[3] += d4[3];
            q2f4(u[q][1], d4); acc[4] += d4[0]; acc[5] += d4[1]; acc[6] += d4[2]; acc[7] += d4[3];
            q2f4(u[q][2], d4); acc[8] += d4[0]; acc[9] += d4[1]; acc[10] += d4[2]; acc[11] += d4[3];
            q2f4(u[q][3], d4); acc[12] += d4[0]; acc[13] += d4[1]; acc[14] += d4[2]; acc[15] += d4[3];
        }
    }

    u32x4 us = *reinterpret_cast<const u32x4*>(tbl + (size_t)node * 128);
    float sdec[16];
    q2f4(us[0], sdec); q2f4(us[1], sdec + 4); q2f4(us[2], sdec + 8); q2f4(us[3], sdec + 12);
    const u32x4* xp = reinterpret_cast<const u32x4*>(xfc + (size_t)node * 128 + c0);
    u32x4 x0 = xp[0], x1 = xp[1];
    uint xw[8] = {x0[0], x0[1], x0[2], x0[3], x1[0], x1[1], x1[2], x1[3]};
    float bb[16];
#pragma unroll
    for (int p = 0; p < 4; ++p) {
        float4 bq = *reinterpret_cast<const float4*>(b1 + c0 + p * 4);
        bb[4 * p] = bq.x; bb[4 * p + 1] = bq.y; bb[4 * p + 2] = bq.z; bb[4 * p + 3] = bq.w;
    }
    uint outw[8];
#pragma unroll
    for (int jj = 0; jj < 8; ++jj) {
        int e0 = 2 * jj, e1 = 2 * jj + 1;
        float v0 = fmaxf((acc[e0] + sdec[e0]) * di + bb[e0], 0.f) + bf2f((ushort)(xw[jj] & 0xffff));
        float v1 = fmaxf((acc[e1] + sdec[e1]) * di + bb[e1], 0.f) + bf2f((ushort)(xw[jj] >> 16));
        outw[jj] = (uint)f2bf(v0) | ((uint)f2bf(v1) << 16);
    }
    ushort* hp = h + (size_t)node * 128 + c0;
    u32x4 o0 = {outw[0], outw[1], outw[2], outw[3]};
    u32x4 o1 = {outw[4], outw[5], outw[6], outw[7]};
    *reinterpret_cast<u32x4*>(hp) = o0;
    *reinterpret_cast<u32x4*>(hp + 8) = o1;
}

// ---------------- aggregation 2 + residual + pool (degree-sorted order) ----------------
// pool_c += relu(dinv_i*(sum h2q[s] + h2q[i]) + b2)_c + h_i_c

__global__ __launch_bounds__(256) void k_agg2(
    const int* __restrict__ csr, const int* __restrict__ offs, const int* __restrict__ degE,
    const float* __restrict__ dinv, const uchar* __restrict__ h2q, const ushort* __restrict__ hres,
    const float* __restrict__ b2, float* __restrict__ pooled, const int* __restrict__ order, int n)
{
    __shared__ float lpool[128];
    int t = threadIdx.x;
    if (t < 128) lpool[t] = 0.f;
    __syncthreads();
    int g = t >> 3, li = t & 7;
    int j = blockIdx.x * 32 + g;
    bool valid = j < n;
    int node = valid ? order[j] : 0;
    int off = offs[node];
    int cnt = valid ? degE[node] : 0;
    float di = dinv[node];
    int c0 = li * 16;
    const uchar* tbl = h2q + c0;
    float acc[16];
#pragma unroll
    for (int e = 0; e < 16; ++e) acc[e] = 0.f;

    for (int base = 0; base < cnt; base += 8) {
        u32x4 u[8];
#pragma unroll
        for (int q = 0; q < 8; ++q) {
            int s = csr[off + base + q];
            int id = (base + q < cnt) ? s : n;
            u[q] = *reinterpret_cast<const u32x4*>(tbl + (size_t)id * 128);
        }
#pragma unroll
        for (int q = 0; q < 8; ++q) {
            float d4[4];
            q2f4(u[q][0], d4); acc[0] += d4[0]; acc[1] += d4[1]; acc[2] += d4[2]; acc[3] += d4[3];
            q2f4(u[q][1], d4); acc[4] += d4[0]; acc[5] += d4[1]; acc[6] += d4[2]; acc[7] += d4[3];
            q2f4(u[q][2], d4); acc[8] += d4[0]; acc[9] += d4[1]; acc[10] += d4[2]; acc[11] += d4[3];
            q2f4(u[q][3], d4); acc[12] += d4[0]; acc[13] += d4[1]; acc[14] += d4[2]; acc[15] += d4[3];
        }
    }

    u32x4 us = *reinterpret_cast<const u32x4*>(tbl + (size_t)node * 128);
    float sdec[16];
    q2f4(us[0], sdec); q2f4(us[1], sdec + 4); q2f4(us[2], sdec + 8); q2f4(us[3], sdec + 12);
    const u32x4* rp = reinterpret_cast<const u32x4*>(hres + (size_t)node * 128 + c0);
    u32x4 r0 = rp[0], r1 = rp[1];
    uint rw[8] = {r0[0], r0[1], r0[2], r0[3], r1[0], r1[1], r1[2], r1[3]};
    float bb[16];
#pragma unroll
    for (int p = 0; p < 4; ++p) {
        float4 bq = *reinterpret_cast<const float4*>(b2 + c0 + p * 4);
        bb[4 * p] = bq.x; bb[4 * p + 1] = bq.y; bb[4 * p + 2] = bq.z; bb[4 * p + 3] = bq.w;
    }
    if (valid) {
#pragma unroll
        for (int jj = 0; jj < 8; ++jj) {
            int e0 = 2 * jj, e1 = 2 * jj + 1;
            float v0 = fmaxf((acc[e0] + sdec[e0]) * di + bb[e0], 0.f) + bf2f((ushort)(rw[jj] & 0xffff));
            float v1 = fmaxf((acc[e1] + sdec[e1]) * di + bb[e1], 0.f) + bf2f((ushort)(rw[jj] >> 16));
            atomicAdd(&lpool[c0 + e0], v0);
            atomicAdd(&lpool[c0 + e1], v1);
        }
    }
    __syncthreads();
    if (t < 128) atomicAdd(&pooled[t], lpool[t]);
}

// ---------------- final: sigmoid(mean @ Wfc + bfc) ----------------

__global__ void k_final(const float* __restrict__ pooled, const float* __restrict__ Wfc,
                        const float* __restrict__ bfc, float* __restrict__ out, float invN) {
    int lane = threadIdx.x;
    float s = pooled[2 * lane] * invN * Wfc[2 * lane] +
              pooled[2 * lane + 1] * invN * Wfc[2 * lane + 1];
#pragma unroll
    for (int off = 32; off > 0; off >>= 1) s += __shfl_down(s, off);
    if (lane == 0) out[0] = 1.f / (1.f + expf(-(s + bfc[0])));
}

// ---------------- launch ----------------

extern "C" void kernel_launch(void* const* d_in, const int* in_sizes, int n_in,
                              void* d_out, int out_size, void* d_ws, size_t ws_size,
                              hipStream_t stream) {
    const float* x   = (const float*)d_in[0];
    const int*   ei  = (const int*)d_in[1];
    const float* W1  = (const float*)d_in[2];
    const float* b1  = (const float*)d_in[3];
    const float* W2  = (const float*)d_in[4];
    const float* b2  = (const float*)d_in[5];
    const float* We  = (const float*)d_in[6];
    const float* be  = (const float*)d_in[7];
    const float* Wfc = (const float*)d_in[8];
    const float* bfc = (const float*)d_in[9];
    float* out = (float*)d_out;

    const int N = in_sizes[0] / 128;
    const int E = in_sizes[1] / 2;
    const int* src = ei;
    const int* dst = ei + E;

    char* w = (char*)d_ws;
    size_t off = 0;
    auto take = [&](size_t bytes) -> void* {
        void* p = w + off;
        off = (off + bytes + 255) & ~(size_t)255;
        return p;
    };
    int*    deg    = (int*)take((size_t)N * 4);
    int*    offs   = (int*)take((size_t)N * 4);
    int*    cursor = (int*)take((size_t)N * 4);
    float*  dinv   = (float*)take((size_t)N * 4);
    int*    order  = (int*)take((size_t)N * 4);
    int*    bsum   = (int*)take(1024);
    int*    boff   = (int*)take(1024);
    int*    hist   = (int*)take(256);
    int*    sbase  = (int*)take(256);
    int*    cursB  = (int*)take(256);
    float*  pooled = (float*)take(512);
    int*    csr    = (int*)take((size_t)(E + 64) * 4);
    uchar*  h1q    = (uchar*)take((size_t)(N + 1) * 128);      // row N = zeros
    ushort* xfc    = (ushort*)take((size_t)N * 128 * 2);
    ushort* h      = (ushort*)take((size_t)N * 128 * 2);
    uchar*  h2q    = (uchar*)take((size_t)(N + 1) * 128);      // row N = zeros

    const int nbScan = (N + 1023) / 1024;
    const int nbN = (N + 255) / 256;

    k_init<<<nbN, 256, 0, stream>>>(deg, cursor, hist, cursB, pooled,
                                    h1q + (size_t)N * 128, h2q + (size_t)N * 128, N);
    k_degree<<<2048, 256, 0, stream>>>(dst, deg, E, N);
    k_dinv<<<nbN, 256, 0, stream>>>(deg, dinv, N);
    k_scan_a<<<nbScan, 256, 0, stream>>>(deg, bsum, N);
    k_scan_b<<<1, 256, 0, stream>>>(bsum, boff, nbScan);
    k_scan_c<<<nbScan, 256, 0, stream>>>(deg, boff, offs, N);
    k_fill<<<2048, 256, 0, stream>>>(src, dst, offs, cursor, csr, E, N);
    k_hist<<<nbN, 256, 0, stream>>>(deg, hist, N);
    k_sortscan<<<1, 64, 0, stream>>>(hist, sbase);
    k_scatter<<<nbN, 256, 0, stream>>>(deg, sbase, cursB, order, N);

    k_gemm1<<<(N + 127) / 128, 512, 0, stream>>>(x, W1, We, be, dinv, h1q, xfc, N);
    k_agg1<<<(N + 31) / 32, 256, 0, stream>>>(csr, offs, deg, dinv, h1q, xfc, b1, h, order, N);
    k_gemm2<<<(N + 127) / 128, 512, 0, stream>>>(h, W2, dinv, h2q, N);
    k_agg2<<<(N + 31) / 32, 256, 0, stream>>>(csr, offs, deg, dinv, h2q, h, b2, pooled, order, N);
    k_final<<<1, 64, 0, stream>>>(pooled, Wfc, bfc, out, 1.0f / (float)N);
}

// Round 14
// 412.737 us; speedup vs baseline: 2.2461x; 2.2461x over previous
//
#include <hip/hip_runtime.h>
#include <hip/hip_bf16.h>

typedef unsigned int uint;
typedef unsigned short ushort;
typedef unsigned char uchar;
typedef __attribute__((ext_vector_type(8))) short short8;
typedef __attribute__((ext_vector_type(4))) float f32x4;
typedef __attribute__((ext_vector_type(4))) uint u32x4;

__device__ __forceinline__ float bf2f(ushort u) {
    union { uint i; float f; } v; v.i = ((uint)u) << 16; return v.f;
}
__device__ __forceinline__ ushort f2bf(float f) {
    union { float f; uint i; } v; v.f = f;
    uint x = v.i;
    uint r = (x + 0x7FFFu + ((x >> 16) & 1u)) >> 16;
    return (ushort)r;
}
// fp8 e4m3 encode via HW cvt
__device__ __forceinline__ uchar f2q(float f) {
    return (uchar)(__builtin_amdgcn_cvt_pk_fp8_f32(f, 0.f, 0, false) & 0xFF);
}
// decode 4 fp8 from a word (literal selectors required)
__device__ __forceinline__ void q2f4(uint w, float* o) {
    o[0] = __builtin_amdgcn_cvt_f32_fp8(w, 0);
    o[1] = __builtin_amdgcn_cvt_f32_fp8(w, 1);
    o[2] = __builtin_amdgcn_cvt_f32_fp8(w, 2);
    o[3] = __builtin_amdgcn_cvt_f32_fp8(w, 3);
}

// ---------------- init: all zeroing in one launch ----------------

__global__ void k_init(int* __restrict__ deg, int* __restrict__ cursor,
                       int* __restrict__ hist, int* __restrict__ cursB,
                       float* __restrict__ pooled,
                       uchar* __restrict__ h1qN, uchar* __restrict__ h2qN, int n) {
    int i = blockIdx.x * 256 + threadIdx.x;
    if (i < n) { deg[i] = 0; cursor[i] = 0; }
    if (i < 64) { hist[i] = 0; cursB[i] = 0; }
    if (i < 128) pooled[i] = 0.f;
    if (i < 32) {
        reinterpret_cast<uint*>(h1qN)[i] = 0;      // zero row N of fp8 tables
        reinterpret_cast<uint*>(h2qN)[i] = 0;
    }
}

// ---------------- graph prep ----------------
// Binned by dst range (bin = blockIdx & 7): each 64B line of deg/cursor/csr
// is written by one XCD only -> no cross-XCD partial-line writeback (R5 fix).

__global__ void k_degree(const int* __restrict__ dst, int* __restrict__ deg,
                         int e, int n) {
    int bin = blockIdx.x & 7;
    int sub = blockIdx.x >> 3;
    int nsub = gridDim.x >> 3;
    int q = (n + 7) >> 3;
    int lo = bin * q, hi = min(n, lo + q);
    for (int i = sub * 256 + threadIdx.x; i < e; i += nsub * 256) {
        int d = dst[i];
        if (d >= lo && d < hi) atomicAdd(&deg[d], 1);
    }
}

__global__ void k_dinv(const int* __restrict__ deg, float* __restrict__ dinv, int n) {
    int i = blockIdx.x * 256 + threadIdx.x;
    if (i < n) dinv[i] = rsqrtf((float)deg[i] + 1.0f);  // +1 self-loop
}

// 3-kernel exclusive scan of edge-degree -> offsets. chunk = 1024/block.
__global__ void k_scan_a(const int* __restrict__ deg, int* __restrict__ bsum, int n) {
    __shared__ int sd[256];
    int t = threadIdx.x;
    int base = blockIdx.x * 1024 + t * 4;
    int s = 0;
#pragma unroll
    for (int j = 0; j < 4; ++j) { int idx = base + j; if (idx < n) s += deg[idx]; }
    sd[t] = s; __syncthreads();
    for (int off = 1; off < 256; off <<= 1) {
        int v = (t >= off) ? sd[t - off] : 0;
        __syncthreads();
        sd[t] += v;
        __syncthreads();
    }
    if (t == 255) bsum[blockIdx.x] = sd[255];
}

__global__ void k_scan_b(const int* __restrict__ bsum, int* __restrict__ boff, int nb) {
    __shared__ int sd[256];
    int t = threadIdx.x;
    int v0 = (t < nb) ? bsum[t] : 0;
    sd[t] = v0; __syncthreads();
    for (int off = 1; off < 256; off <<= 1) {
        int v = (t >= off) ? sd[t - off] : 0;
        __syncthreads();
        sd[t] += v;
        __syncthreads();
    }
    if (t < nb) boff[t] = sd[t] - v0;  // exclusive
}

__global__ void k_scan_c(const int* __restrict__ deg, const int* __restrict__ boff,
                         int* __restrict__ offs, int n) {
    __shared__ int sd[256];
    int t = threadIdx.x;
    int base = blockIdx.x * 1024 + t * 4;
    int vals[4]; int s = 0;
#pragma unroll
    for (int j = 0; j < 4; ++j) {
        int idx = base + j;
        vals[j] = (idx < n) ? deg[idx] : 0;
        s += vals[j];
    }
    sd[t] = s; __syncthreads();
    for (int off = 1; off < 256; off <<= 1) {
        int v = (t >= off) ? sd[t - off] : 0;
        __syncthreads();
        sd[t] += v;
        __syncthreads();
    }
    int run = boff[blockIdx.x] + (sd[t] - s);
#pragma unroll
    for (int j = 0; j < 4; ++j) {
        int idx = base + j;
        if (idx < n) { offs[idx] = run; run += vals[j]; }
    }
}

__global__ void k_fill(const int* __restrict__ src, const int* __restrict__ dst,
                       const int* __restrict__ offs, int* __restrict__ cursor,
                       int* __restrict__ csr, int e, int n) {
    int bin = blockIdx.x & 7;
    int sub = blockIdx.x >> 3;
    int nsub = gridDim.x >> 3;
    int q = (n + 7) >> 3;
    int lo = bin * q, hi = min(n, lo + q);
    for (int i = sub * 256 + threadIdx.x; i < e; i += nsub * 256) {
        int d = dst[i];
        if (d >= lo && d < hi) {
            int p = offs[d] + atomicAdd(&cursor[d], 1);
            csr[p] = src[i];
        }
    }
}

// ---------------- counting sort of nodes by degree (key clamped to 63) ------
// R13 post-mortem: naive per-thread global atomics into 64 bins = 262 µs of
// cross-XCD same-address serialization. Fix: LDS pre-aggregation — per-block
// LDS histogram + <=64 global atomics per block (Guideline 12).

__global__ void k_hist(const int* __restrict__ deg, int* __restrict__ hist, int n) {
    __shared__ int lh[64];
    int t = threadIdx.x;
    if (t < 64) lh[t] = 0;
    __syncthreads();
    int i = blockIdx.x * 256 + t;
    if (i < n) atomicAdd(&lh[min(deg[i], 63)], 1);
    __syncthreads();
    if (t < 64 && lh[t] > 0) atomicAdd(&hist[t], lh[t]);
}

__global__ void k_sortscan(const int* __restrict__ hist, int* __restrict__ base) {
    __shared__ int sd[64];
    int t = threadIdx.x;
    int v0 = hist[t];
    sd[t] = v0; __syncthreads();
    for (int off = 1; off < 64; off <<= 1) {
        int v = (t >= off) ? sd[t - off] : 0;
        __syncthreads();
        sd[t] += v;
        __syncthreads();
    }
    base[t] = sd[t] - v0;  // exclusive
}

// LDS rank within (block,bin) + one global atomic per (block,bin) for the base.
// Intra-bin order is schedule-dependent; order[] is only a processing
// permutation (outputs indexed by true node id; pool is order-free).
__global__ void k_scatter(const int* __restrict__ deg, const int* __restrict__ base,
                          int* __restrict__ cursB, int* __restrict__ order, int n) {
    __shared__ int lcnt[64], lbase[64];
    int t = threadIdx.x;
    if (t < 64) lcnt[t] = 0;
    __syncthreads();
    int i = blockIdx.x * 256 + t;
    bool valid = i < n;
    int b = 0, r = 0;
    if (valid) {
        b = min(deg[i], 63);
        r = atomicAdd(&lcnt[b], 1);          // LDS: fast
    }
    __syncthreads();
    if (t < 64) lbase[t] = (lcnt[t] > 0) ? atomicAdd(&cursB[t], lcnt[t]) : 0;
    __syncthreads();
    if (valid) order[base[b] + lbase[b] + r] = i;
}

// ---------------- GEMM1: h1q = fp8((x@W1)*dinv), xfc = bf16(relu(x@We+be)) ----------------

__global__ __launch_bounds__(512) void k_gemm1(
    const float* __restrict__ x, const float* __restrict__ W1, const float* __restrict__ We,
    const float* __restrict__ be, const float* __restrict__ dinv,
    uchar* __restrict__ h1q, ushort* __restrict__ xfc, int n)
{
    __shared__ __align__(16) ushort Bt[256][72];  // [col][k_local], pad 72 for banks
    int tid = threadIdx.x;
    int w = tid >> 6, lane = tid & 63;
    int ln15 = lane & 15, g = lane >> 4;
    int rowBase = blockIdx.x * 128 + w * 16;
    int r = rowBase + ln15;
    bool valid = r < n;

    short8 a[4];
#pragma unroll
    for (int ks = 0; ks < 4; ++ks) {
        float4 f0 = make_float4(0.f, 0.f, 0.f, 0.f), f1 = f0;
        if (valid) {
            const float* p = x + (size_t)r * 128 + ks * 32 + g * 8;
            f0 = *reinterpret_cast<const float4*>(p);
            f1 = *reinterpret_cast<const float4*>(p + 4);
        }
        short8 v;
        v[0] = (short)f2bf(f0.x); v[1] = (short)f2bf(f0.y);
        v[2] = (short)f2bf(f0.z); v[3] = (short)f2bf(f0.w);
        v[4] = (short)f2bf(f1.x); v[5] = (short)f2bf(f1.y);
        v[6] = (short)f2bf(f1.z); v[7] = (short)f2bf(f1.w);
        a[ks] = v;
    }

    f32x4 acc[16];
#pragma unroll
    for (int i = 0; i < 16; ++i) acc[i] = (f32x4){0.f, 0.f, 0.f, 0.f};

    for (int s = 0; s < 2; ++s) {
        for (int i = tid; i < 8192; i += 512) {
            int kl = i >> 7, j = i & 127;
            int kg = s * 64 + kl;
            Bt[j][kl]       = f2bf(W1[kg * 128 + j]);
            Bt[128 + j][kl] = f2bf(We[kg * 128 + j]);
        }
        __syncthreads();
#pragma unroll
        for (int t2 = 0; t2 < 2; ++t2) {
            short8 af = a[s * 2 + t2];
#pragma unroll
            for (int jf = 0; jf < 16; ++jf) {
                short8 bf = *reinterpret_cast<const short8*>(&Bt[jf * 16 + ln15][t2 * 32 + g * 8]);
                acc[jf] = __builtin_amdgcn_mfma_f32_16x16x32_bf16(af, bf, acc[jf], 0, 0, 0);
            }
        }
        __syncthreads();
    }

    float dv[4];
#pragma unroll
    for (int q = 0; q < 4; ++q) {
        int rr = rowBase + g * 4 + q;
        dv[q] = (rr < n) ? dinv[rr] : 0.f;
    }

    // D layout: col = lane&15, row = (lane>>4)*4 + q
#pragma unroll
    for (int jf = 0; jf < 16; ++jf) {
        int col = jf * 16 + ln15;
#pragma unroll
        for (int q = 0; q < 4; ++q) {
            int rr = rowBase + g * 4 + q;
            if (rr < n) {
                float v = acc[jf][q];
                if (col < 128) {
                    h1q[(size_t)rr * 128 + col] = f2q(v * dv[q]);
                } else {
                    float vv = fmaxf(v + be[col - 128], 0.f);
                    xfc[(size_t)rr * 128 + (col - 128)] = f2bf(vv);
                }
            }
        }
    }
}

// ---------------- GEMM2: h2q = fp8((h@W2)*dinv) (bf16 in) ----------------

__global__ __launch_bounds__(512) void k_gemm2(
    const ushort* __restrict__ h, const float* __restrict__ W2, const float* __restrict__ dinv,
    uchar* __restrict__ h2q, int n)
{
    __shared__ __align__(16) ushort Bt[128][72];
    int tid = threadIdx.x;
    int w = tid >> 6, lane = tid & 63;
    int ln15 = lane & 15, g = lane >> 4;
    int rowBase = blockIdx.x * 128 + w * 16;
    int r = rowBase + ln15;
    bool valid = r < n;

    short8 a[4];
#pragma unroll
    for (int ks = 0; ks < 4; ++ks) {
        short8 v = (short8){0,0,0,0,0,0,0,0};
        if (valid) v = *reinterpret_cast<const short8*>(h + (size_t)r * 128 + ks * 32 + g * 8);
        a[ks] = v;
    }

    f32x4 acc[8];
#pragma unroll
    for (int i = 0; i < 8; ++i) acc[i] = (f32x4){0.f, 0.f, 0.f, 0.f};

    for (int s = 0; s < 2; ++s) {
        for (int i = tid; i < 8192; i += 512) {
            int kl = i >> 7, j = i & 127;
            Bt[j][kl] = f2bf(W2[(s * 64 + kl) * 128 + j]);
        }
        __syncthreads();
#pragma unroll
        for (int t2 = 0; t2 < 2; ++t2) {
            short8 af = a[s * 2 + t2];
#pragma unroll
            for (int jf = 0; jf < 8; ++jf) {
                short8 bf = *reinterpret_cast<const short8*>(&Bt[jf * 16 + ln15][t2 * 32 + g * 8]);
                acc[jf] = __builtin_amdgcn_mfma_f32_16x16x32_bf16(af, bf, acc[jf], 0, 0, 0);
            }
        }
        __syncthreads();
    }

    float dv[4];
#pragma unroll
    for (int q = 0; q < 4; ++q) {
        int rr = rowBase + g * 4 + q;
        dv[q] = (rr < n) ? dinv[rr] : 0.f;
    }

#pragma unroll
    for (int jf = 0; jf < 8; ++jf) {
        int col = jf * 16 + ln15;
#pragma unroll
        for (int q = 0; q < 4; ++q) {
            int rr = rowBase + g * 4 + q;
            if (rr < n) h2q[(size_t)rr * 128 + col] = f2q(acc[jf][q] * dv[q]);
        }
    }
}

// ---------------- aggregation 1 (degree-sorted order) ----------------
// h_i = relu(dinv_i*(sum_{s in N(i)} h1q[s] + h1q[i]) + b1) + xfc_i   (bf16 out)
// 8-lane group per node (best measured shape, R5: 8 rows x 16B per gather
// instruction). Nodes processed in degree-sorted order -> all 8 groups of a
// wave run the same batch count (no divergence waste). Tail edges clamp to
// zero-row n. csr padded +64.

__global__ __launch_bounds__(256) void k_agg1(
    const int* __restrict__ csr, const int* __restrict__ offs, const int* __restrict__ degE,
    const float* __restrict__ dinv, const uchar* __restrict__ h1q, const ushort* __restrict__ xfc,
    const float* __restrict__ b1, ushort* __restrict__ h, const int* __restrict__ order, int n)
{
    int t = threadIdx.x;
    int g = t >> 3, li = t & 7;
    int j = blockIdx.x * 32 + g;
    if (j >= n) return;
    int node = order[j];
    int off = offs[node], cnt = degE[node];
    float di = dinv[node];
    int c0 = li * 16;
    const uchar* tbl = h1q + c0;
    float acc[16];
#pragma unroll
    for (int e = 0; e < 16; ++e) acc[e] = 0.f;

    for (int base = 0; base < cnt; base += 8) {
        u32x4 u[8];
#pragma unroll
        for (int q = 0; q < 8; ++q) {
            int s = csr[off + base + q];            // group-uniform
            int id = (base + q < cnt) ? s : n;      // zero row for tail
            u[q] = *reinterpret_cast<const u32x4*>(tbl + (size_t)id * 128);
        }
#pragma unroll
        for (int q = 0; q < 8; ++q) {
            float d4[4];
            q2f4(u[q][0], d4); acc[0] += d4[0]; acc[1] += d4[1]; acc[2] += d4[2]; acc[3] += d4[3];
            q2f4(u[q][1], d4); acc[4] += d4[0]; acc[5] += d4[1]; acc[6] += d4[2]; acc[7] += d4[3];
            q2f4(u[q][2], d4); acc[8] += d4[0]; acc[9] += d4[1]; acc[10] += d4[2]; acc[11] += d4[3];
            q2f4(u[q][3], d4); acc[12] += d4[0]; acc[13] += d4[1]; acc[14] += d4[2]; acc[15] += d4[3];
        }
    }

    u32x4 us = *reinterpret_cast<const u32x4*>(tbl + (size_t)node * 128);
    float sdec[16];
    q2f4(us[0], sdec); q2f4(us[1], sdec + 4); q2f4(us[2], sdec + 8); q2f4(us[3], sdec + 12);
    const u32x4* xp = reinterpret_cast<const u32x4*>(xfc + (size_t)node * 128 + c0);
    u32x4 x0 = xp[0], x1 = xp[1];
    uint xw[8] = {x0[0], x0[1], x0[2], x0[3], x1[0], x1[1], x1[2], x1[3]};
    float bb[16];
#pragma unroll
    for (int p = 0; p < 4; ++p) {
        float4 bq = *reinterpret_cast<const float4*>(b1 + c0 + p * 4);
        bb[4 * p] = bq.x; bb[4 * p + 1] = bq.y; bb[4 * p + 2] = bq.z; bb[4 * p + 3] = bq.w;
    }
    uint outw[8];
#pragma unroll
    for (int jj = 0; jj < 8; ++jj) {
        int e0 = 2 * jj, e1 = 2 * jj + 1;
        float v0 = fmaxf((acc[e0] + sdec[e0]) * di + bb[e0], 0.f) + bf2f((ushort)(xw[jj] & 0xffff));
        float v1 = fmaxf((acc[e1] + sdec[e1]) * di + bb[e1], 0.f) + bf2f((ushort)(xw[jj] >> 16));
        outw[jj] = (uint)f2bf(v0) | ((uint)f2bf(v1) << 16);
    }
    ushort* hp = h + (size_t)node * 128 + c0;
    u32x4 o0 = {outw[0], outw[1], outw[2], outw[3]};
    u32x4 o1 = {outw[4], outw[5], outw[6], outw[7]};
    *reinterpret_cast<u32x4*>(hp) = o0;
    *reinterpret_cast<u32x4*>(hp + 8) = o1;
}

// ---------------- aggregation 2 + residual + pool (degree-sorted order) ----------------
// pool_c += relu(dinv_i*(sum h2q[s] + h2q[i]) + b2)_c + h_i_c

__global__ __launch_bounds__(256) void k_agg2(
    const int* __restrict__ csr, const int* __restrict__ offs, const int* __restrict__ degE,
    const float* __restrict__ dinv, const uchar* __restrict__ h2q, const ushort* __restrict__ hres,
    const float* __restrict__ b2, float* __restrict__ pooled, const int* __restrict__ order, int n)
{
    __shared__ float lpool[128];
    int t = threadIdx.x;
    if (t < 128) lpool[t] = 0.f;
    __syncthreads();
    int g = t >> 3, li = t & 7;
    int j = blockIdx.x * 32 + g;
    bool valid = j < n;
    int node = valid ? order[j] : 0;
    int off = offs[node];
    int cnt = valid ? degE[node] : 0;
    float di = dinv[node];
    int c0 = li * 16;
    const uchar* tbl = h2q + c0;
    float acc[16];
#pragma unroll
    for (int e = 0; e < 16; ++e) acc[e] = 0.f;

    for (int base = 0; base < cnt; base += 8) {
        u32x4 u[8];
#pragma unroll
        for (int q = 0; q < 8; ++q) {
            int s = csr[off + base + q];
            int id = (base + q < cnt) ? s : n;
            u[q] = *reinterpret_cast<const u32x4*>(tbl + (size_t)id * 128);
        }
#pragma unroll
        for (int q = 0; q < 8; ++q) {
            float d4[4];
            q2f4(u[q][0], d4); acc[0] += d4[0]; acc[1] += d4[1]; acc[2] += d4[2]; acc[3] += d4[3];
            q2f4(u[q][1], d4); acc[4] += d4[0]; acc[5] += d4[1]; acc[6] += d4[2]; acc[7] += d4[3];
            q2f4(u[q][2], d4); acc[8] += d4[0]; acc[9] += d4[1]; acc[10] += d4[2]; acc[11] += d4[3];
            q2f4(u[q][3], d4); acc[12] += d4[0]; acc[13] += d4[1]; acc[14] += d4[2]; acc[15] += d4[3];
        }
    }

    u32x4 us = *reinterpret_cast<const u32x4*>(tbl + (size_t)node * 128);
    float sdec[16];
    q2f4(us[0], sdec); q2f4(us[1], sdec + 4); q2f4(us[2], sdec + 8); q2f4(us[3], sdec + 12);
    const u32x4* rp = reinterpret_cast<const u32x4*>(hres + (size_t)node * 128 + c0);
    u32x4 r0 = rp[0], r1 = rp[1];
    uint rw[8] = {r0[0], r0[1], r0[2], r0[3], r1[0], r1[1], r1[2], r1[3]};
    float bb[16];
#pragma unroll
    for (int p = 0; p < 4; ++p) {
        float4 bq = *reinterpret_cast<const float4*>(b2 + c0 + p * 4);
        bb[4 * p] = bq.x; bb[4 * p + 1] = bq.y; bb[4 * p + 2] = bq.z; bb[4 * p + 3] = bq.w;
    }
    if (valid) {
#pragma unroll
        for (int jj = 0; jj < 8; ++jj) {
            int e0 = 2 * jj, e1 = 2 * jj + 1;
            float v0 = fmaxf((acc[e0] + sdec[e0]) * di + bb[e0], 0.f) + bf2f((ushort)(rw[jj] & 0xffff));
            float v1 = fmaxf((acc[e1] + sdec[e1]) * di + bb[e1], 0.f) + bf2f((ushort)(rw[jj] >> 16));
            atomicAdd(&lpool[c0 + e0], v0);
            atomicAdd(&lpool[c0 + e1], v1);
        }
    }
    __syncthreads();
    if (t < 128) atomicAdd(&pooled[t], lpool[t]);
}

// ---------------- final: sigmoid(mean @ Wfc + bfc) ----------------

__global__ void k_final(const float* __restrict__ pooled, const float* __restrict__ Wfc,
                        const float* __restrict__ bfc, float* __restrict__ out, float invN) {
    int lane = threadIdx.x;
    float s = pooled[2 * lane] * invN * Wfc[2 * lane] +
              pooled[2 * lane + 1] * invN * Wfc[2 * lane + 1];
#pragma unroll
    for (int off = 32; off > 0; off >>= 1) s += __shfl_down(s, off);
    if (lane == 0) out[0] = 1.f / (1.f + expf(-(s + bfc[0])));
}

// ---------------- launch ----------------

extern "C" void kernel_launch(void* const* d_in, const int* in_sizes, int n_in,
                              void* d_out, int out_size, void* d_ws, size_t ws_size,
                              hipStream_t stream) {
    const float* x   = (const float*)d_in[0];
    const int*   ei  = (const int*)d_in[1];
    const float* W1  = (const float*)d_in[2];
    const float* b1  = (const float*)d_in[3];
    const float* W2  = (const float*)d_in[4];
    const float* b2  = (const float*)d_in[5];
    const float* We  = (const float*)d_in[6];
    const float* be  = (const float*)d_in[7];
    const float* Wfc = (const float*)d_in[8];
    const float* bfc = (const float*)d_in[9];
    float* out = (float*)d_out;

    const int N = in_sizes[0] / 128;
    const int E = in_sizes[1] / 2;
    const int* src = ei;
    const int* dst = ei + E;

    char* w = (char*)d_ws;
    size_t off = 0;
    auto take = [&](size_t bytes) -> void* {
        void* p = w + off;
        off = (off + bytes + 255) & ~(size_t)255;
        return p;
    };
    int*    deg    = (int*)take((size_t)N * 4);
    int*    offs   = (int*)take((size_t)N * 4);
    int*    cursor = (int*)take((size_t)N * 4);
    float*  dinv   = (float*)take((size_t)N * 4);
    int*    order  = (int*)take((size_t)N * 4);
    int*    bsum   = (int*)take(1024);
    int*    boff   = (int*)take(1024);
    int*    hist   = (int*)take(256);
    int*    sbase  = (int*)take(256);
    int*    cursB  = (int*)take(256);
    float*  pooled = (float*)take(512);
    int*    csr    = (int*)take((size_t)(E + 64) * 4);
    uchar*  h1q    = (uchar*)take((size_t)(N + 1) * 128);      // row N = zeros
    ushort* xfc    = (ushort*)take((size_t)N * 128 * 2);
    ushort* h      = (ushort*)take((size_t)N * 128 * 2);
    uchar*  h2q    = (uchar*)take((size_t)(N + 1) * 128);      // row N = zeros

    const int nbScan = (N + 1023) / 1024;
    const int nbN = (N + 255) / 256;

    k_init<<<nbN, 256, 0, stream>>>(deg, cursor, hist, cursB, pooled,
                                    h1q + (size_t)N * 128, h2q + (size_t)N * 128, N);
    k_degree<<<2048, 256, 0, stream>>>(dst, deg, E, N);
    k_dinv<<<nbN, 256, 0, stream>>>(deg, dinv, N);
    k_scan_a<<<nbScan, 256, 0, stream>>>(deg, bsum, N);
    k_scan_b<<<1, 256, 0, stream>>>(bsum, boff, nbScan);
    k_scan_c<<<nbScan, 256, 0, stream>>>(deg, boff, offs, N);
    k_fill<<<2048, 256, 0, stream>>>(src, dst, offs, cursor, csr, E, N);
    k_hist<<<nbN, 256, 0, stream>>>(deg, hist, N);
    k_sortscan<<<1, 64, 0, stream>>>(hist, sbase);
    k_scatter<<<nbN, 256, 0, stream>>>(deg, sbase, cursB, order, N);

    k_gemm1<<<(N + 127) / 128, 512, 0, stream>>>(x, W1, We, be, dinv, h1q, xfc, N);
    k_agg1<<<(N + 31) / 32, 256, 0, stream>>>(csr, offs, deg, dinv, h1q, xfc, b1, h, order, N);
    k_gemm2<<<(N + 127) / 128, 512, 0, stream>>>(h, W2, dinv, h2q, N);
    k_agg2<<<(N + 31) / 32, 256, 0, stream>>>(csr, offs, deg, dinv, h2q, h, b2, pooled, order, N);
    k_final<<<1, 64, 0, stream>>>(pooled, Wfc, bfc, out, 1.0f / (float)N);
}

// Round 15
// 396.411 us; speedup vs baseline: 2.3387x; 1.0412x over previous
//
#include <hip/hip_runtime.h>
#include <hip/hip_bf16.h>

typedef unsigned int uint;
typedef unsigned short ushort;
typedef unsigned char uchar;
typedef __attribute__((ext_vector_type(8))) short short8;
typedef __attribute__((ext_vector_type(4))) float f32x4;
typedef __attribute__((ext_vector_type(4))) uint u32x4;

__device__ __forceinline__ float bf2f(ushort u) {
    union { uint i; float f; } v; v.i = ((uint)u) << 16; return v.f;
}
__device__ __forceinline__ ushort f2bf(float f) {
    union { float f; uint i; } v; v.f = f;
    uint x = v.i;
    uint r = (x + 0x7FFFu + ((x >> 16) & 1u)) >> 16;
    return (ushort)r;
}
// fp8 e4m3 encode via HW cvt
__device__ __forceinline__ uchar f2q(float f) {
    return (uchar)(__builtin_amdgcn_cvt_pk_fp8_f32(f, 0.f, 0, false) & 0xFF);
}
// decode 4 fp8 from a word (literal selectors required)
__device__ __forceinline__ void q2f4(uint w, float* o) {
    o[0] = __builtin_amdgcn_cvt_f32_fp8(w, 0);
    o[1] = __builtin_amdgcn_cvt_f32_fp8(w, 1);
    o[2] = __builtin_amdgcn_cvt_f32_fp8(w, 2);
    o[3] = __builtin_amdgcn_cvt_f32_fp8(w, 3);
}

// ---------------- init: all zeroing in one launch ----------------

__global__ void k_init(int* __restrict__ deg, int* __restrict__ cursor,
                       float* __restrict__ pooled,
                       uchar* __restrict__ h1qN, uchar* __restrict__ h2qN, int n) {
    int i = blockIdx.x * 256 + threadIdx.x;
    if (i < n) { deg[i] = 0; cursor[i] = 0; }
    if (i < 128) pooled[i] = 0.f;
    if (i < 32) {
        reinterpret_cast<uint*>(h1qN)[i] = 0;      // zero row N of fp8 tables
        reinterpret_cast<uint*>(h2qN)[i] = 0;
    }
}

// ---------------- graph prep ----------------
// Binned by dst range (bin = blockIdx & 7): each 64B line of deg/cursor/csr
// is written by one XCD only -> no cross-XCD partial-line writeback (R5 fix).

__global__ void k_degree(const int* __restrict__ dst, int* __restrict__ deg,
                         int e, int n) {
    int bin = blockIdx.x & 7;
    int sub = blockIdx.x >> 3;
    int nsub = gridDim.x >> 3;
    int q = (n + 7) >> 3;
    int lo = bin * q, hi = min(n, lo + q);
    for (int i = sub * 256 + threadIdx.x; i < e; i += nsub * 256) {
        int d = dst[i];
        if (d >= lo && d < hi) atomicAdd(&deg[d], 1);
    }
}

__global__ void k_dinv(const int* __restrict__ deg, float* __restrict__ dinv, int n) {
    int i = blockIdx.x * 256 + threadIdx.x;
    if (i < n) dinv[i] = rsqrtf((float)deg[i] + 1.0f);  // +1 self-loop
}

// 3-kernel exclusive scan of edge-degree -> offsets. chunk = 1024/block.
__global__ void k_scan_a(const int* __restrict__ deg, int* __restrict__ bsum, int n) {
    __shared__ int sd[256];
    int t = threadIdx.x;
    int base = blockIdx.x * 1024 + t * 4;
    int s = 0;
#pragma unroll
    for (int j = 0; j < 4; ++j) { int idx = base + j; if (idx < n) s += deg[idx]; }
    sd[t] = s; __syncthreads();
    for (int off = 1; off < 256; off <<= 1) {
        int v = (t >= off) ? sd[t - off] : 0;
        __syncthreads();
        sd[t] += v;
        __syncthreads();
    }
    if (t == 255) bsum[blockIdx.x] = sd[255];
}

__global__ void k_scan_b(const int* __restrict__ bsum, int* __restrict__ boff, int nb) {
    __shared__ int sd[256];
    int t = threadIdx.x;
    int v0 = (t < nb) ? bsum[t] : 0;
    sd[t] = v0; __syncthreads();
    for (int off = 1; off < 256; off <<= 1) {
        int v = (t >= off) ? sd[t - off] : 0;
        __syncthreads();
        sd[t] += v;
        __syncthreads();
    }
    if (t < nb) boff[t] = sd[t] - v0;  // exclusive
}

__global__ void k_scan_c(const int* __restrict__ deg, const int* __restrict__ boff,
                         int* __restrict__ offs, int n) {
    __shared__ int sd[256];
    int t = threadIdx.x;
    int base = blockIdx.x * 1024 + t * 4;
    int vals[4]; int s = 0;
#pragma unroll
    for (int j = 0; j < 4; ++j) {
        int idx = base + j;
        vals[j] = (idx < n) ? deg[idx] : 0;
        s += vals[j];
    }
    sd[t] = s; __syncthreads();
    for (int off = 1; off < 256; off <<= 1) {
        int v = (t >= off) ? sd[t - off] : 0;
        __syncthreads();
        sd[t] += v;
        __syncthreads();
    }
    int run = boff[blockIdx.x] + (sd[t] - s);
#pragma unroll
    for (int j = 0; j < 4; ++j) {
        int idx = base + j;
        if (idx < n) { offs[idx] = run; run += vals[j]; }
    }
}

__global__ void k_fill(const int* __restrict__ src, const int* __restrict__ dst,
                       const int* __restrict__ offs, int* __restrict__ cursor,
                       int* __restrict__ csr, int e, int n) {
    int bin = blockIdx.x & 7;
    int sub = blockIdx.x >> 3;
    int nsub = gridDim.x >> 3;
    int q = (n + 7) >> 3;
    int lo = bin * q, hi = min(n, lo + q);
    for (int i = sub * 256 + threadIdx.x; i < e; i += nsub * 256) {
        int d = dst[i];
        if (d >= lo && d < hi) {
            int p = offs[d] + atomicAdd(&cursor[d], 1);
            csr[p] = src[i];
        }
    }
}

// ---------------- GEMM1: h1q = fp8((x@W1)*dinv), xfc = bf16(relu(x@We+be)) ----------------

__global__ __launch_bounds__(512) void k_gemm1(
    const float* __restrict__ x, const float* __restrict__ W1, const float* __restrict__ We,
    const float* __restrict__ be, const float* __restrict__ dinv,
    uchar* __restrict__ h1q, ushort* __restrict__ xfc, int n)
{
    __shared__ __align__(16) ushort Bt[256][72];  // [col][k_local], pad 72 for banks
    int tid = threadIdx.x;
    int w = tid >> 6, lane = tid & 63;
    int ln15 = lane & 15, g = lane >> 4;
    int rowBase = blockIdx.x * 128 + w * 16;
    int r = rowBase + ln15;
    bool valid = r < n;

    short8 a[4];
#pragma unroll
    for (int ks = 0; ks < 4; ++ks) {
        float4 f0 = make_float4(0.f, 0.f, 0.f, 0.f), f1 = f0;
        if (valid) {
            const float* p = x + (size_t)r * 128 + ks * 32 + g * 8;
            f0 = *reinterpret_cast<const float4*>(p);
            f1 = *reinterpret_cast<const float4*>(p + 4);
        }
        short8 v;
        v[0] = (short)f2bf(f0.x); v[1] = (short)f2bf(f0.y);
        v[2] = (short)f2bf(f0.z); v[3] = (short)f2bf(f0.w);
        v[4] = (short)f2bf(f1.x); v[5] = (short)f2bf(f1.y);
        v[6] = (short)f2bf(f1.z); v[7] = (short)f2bf(f1.w);
        a[ks] = v;
    }

    f32x4 acc[16];
#pragma unroll
    for (int i = 0; i < 16; ++i) acc[i] = (f32x4){0.f, 0.f, 0.f, 0.f};

    for (int s = 0; s < 2; ++s) {
        for (int i = tid; i < 8192; i += 512) {
            int kl = i >> 7, j = i & 127;
            int kg = s * 64 + kl;
            Bt[j][kl]       = f2bf(W1[kg * 128 + j]);
            Bt[128 + j][kl] = f2bf(We[kg * 128 + j]);
        }
        __syncthreads();
#pragma unroll
        for (int t2 = 0; t2 < 2; ++t2) {
            short8 af = a[s * 2 + t2];
#pragma unroll
            for (int jf = 0; jf < 16; ++jf) {
                short8 bf = *reinterpret_cast<const short8*>(&Bt[jf * 16 + ln15][t2 * 32 + g * 8]);
                acc[jf] = __builtin_amdgcn_mfma_f32_16x16x32_bf16(af, bf, acc[jf], 0, 0, 0);
            }
        }
        __syncthreads();
    }

    float dv[4];
#pragma unroll
    for (int q = 0; q < 4; ++q) {
        int rr = rowBase + g * 4 + q;
        dv[q] = (rr < n) ? dinv[rr] : 0.f;
    }

    // D layout: col = lane&15, row = (lane>>4)*4 + q
#pragma unroll
    for (int jf = 0; jf < 16; ++jf) {
        int col = jf * 16 + ln15;
#pragma unroll
        for (int q = 0; q < 4; ++q) {
            int rr = rowBase + g * 4 + q;
            if (rr < n) {
                float v = acc[jf][q];
                if (col < 128) {
                    h1q[(size_t)rr * 128 + col] = f2q(v * dv[q]);
                } else {
                    float vv = fmaxf(v + be[col - 128], 0.f);
                    xfc[(size_t)rr * 128 + (col - 128)] = f2bf(vv);
                }
            }
        }
    }
}

// ---------------- GEMM2: h2q = fp8((h@W2)*dinv) (bf16 in) ----------------

__global__ __launch_bounds__(512) void k_gemm2(
    const ushort* __restrict__ h, const float* __restrict__ W2, const float* __restrict__ dinv,
    uchar* __restrict__ h2q, int n)
{
    __shared__ __align__(16) ushort Bt[128][72];
    int tid = threadIdx.x;
    int w = tid >> 6, lane = tid & 63;
    int ln15 = lane & 15, g = lane >> 4;
    int rowBase = blockIdx.x * 128 + w * 16;
    int r = rowBase + ln15;
    bool valid = r < n;

    short8 a[4];
#pragma unroll
    for (int ks = 0; ks < 4; ++ks) {
        short8 v = (short8){0,0,0,0,0,0,0,0};
        if (valid) v = *reinterpret_cast<const short8*>(h + (size_t)r * 128 + ks * 32 + g * 8);
        a[ks] = v;
    }

    f32x4 acc[8];
#pragma unroll
    for (int i = 0; i < 8; ++i) acc[i] = (f32x4){0.f, 0.f, 0.f, 0.f};

    for (int s = 0; s < 2; ++s) {
        for (int i = tid; i < 8192; i += 512) {
            int kl = i >> 7, j = i & 127;
            Bt[j][kl] = f2bf(W2[(s * 64 + kl) * 128 + j]);
        }
        __syncthreads();
#pragma unroll
        for (int t2 = 0; t2 < 2; ++t2) {
            short8 af = a[s * 2 + t2];
#pragma unroll
            for (int jf = 0; jf < 8; ++jf) {
                short8 bf = *reinterpret_cast<const short8*>(&Bt[jf * 16 + ln15][t2 * 32 + g * 8]);
                acc[jf] = __builtin_amdgcn_mfma_f32_16x16x32_bf16(af, bf, acc[jf], 0, 0, 0);
            }
        }
        __syncthreads();
    }

    float dv[4];
#pragma unroll
    for (int q = 0; q < 4; ++q) {
        int rr = rowBase + g * 4 + q;
        dv[q] = (rr < n) ? dinv[rr] : 0.f;
    }

#pragma unroll
    for (int jf = 0; jf < 8; ++jf) {
        int col = jf * 16 + ln15;
#pragma unroll
        for (int q = 0; q < 4; ++q) {
            int rr = rowBase + g * 4 + q;
            if (rr < n) h2q[(size_t)rr * 128 + col] = f2q(acc[jf][q] * dv[q]);
        }
    }
}

// ---------------- aggregation 1 ----------------
// h_i = relu(dinv_i*(sum_{s in N(i)} h1q[s] + h1q[i]) + b1) + xfc_i   (bf16 out)
// 8-lane group per node; lane owns 16 channels (16B fp8 gathers; a group's
// 8 lanes cover the full 128B row in one instruction). 8 edges in flight.
// This shape is the measured floor (~125us): R9-R14 falsified byte-volume,
// in-flight-bytes, address-divergence, and wave-divergence as levers.
// Tail edges clamp to zero-row n. csr padded +64.

__global__ __launch_bounds__(256) void k_agg1(
    const int* __restrict__ csr, const int* __restrict__ offs, const int* __restrict__ degE,
    const float* __restrict__ dinv, const uchar* __restrict__ h1q, const ushort* __restrict__ xfc,
    const float* __restrict__ b1, ushort* __restrict__ h, int n)
{
    int t = threadIdx.x;
    int g = t >> 3, li = t & 7;
    int node = blockIdx.x * 32 + g;
    if (node >= n) return;
    int off = offs[node], cnt = degE[node];
    float di = dinv[node];
    int c0 = li * 16;
    const uchar* tbl = h1q + c0;
    float acc[16];
#pragma unroll
    for (int e = 0; e < 16; ++e) acc[e] = 0.f;

    for (int base = 0; base < cnt; base += 8) {
        u32x4 u[8];
#pragma unroll
        for (int q = 0; q < 8; ++q) {
            int s = csr[off + base + q];            // group-uniform
            int id = (base + q < cnt) ? s : n;      // zero row for tail
            u[q] = *reinterpret_cast<const u32x4*>(tbl + (size_t)id * 128);
        }
#pragma unroll
        for (int q = 0; q < 8; ++q) {
            float d4[4];
            q2f4(u[q][0], d4); acc[0] += d4[0]; acc[1] += d4[1]; acc[2] += d4[2]; acc[3] += d4[3];
            q2f4(u[q][1], d4); acc[4] += d4[0]; acc[5] += d4[1]; acc[6] += d4[2]; acc[7] += d4[3];
            q2f4(u[q][2], d4); acc[8] += d4[0]; acc[9] += d4[1]; acc[10] += d4[2]; acc[11] += d4[3];
            q2f4(u[q][3], d4); acc[12] += d4[0]; acc[13] += d4[1]; acc[14] += d4[2]; acc[15] += d4[3];
        }
    }

    u32x4 us = *reinterpret_cast<const u32x4*>(tbl + (size_t)node * 128);
    float sdec[16];
    q2f4(us[0], sdec); q2f4(us[1], sdec + 4); q2f4(us[2], sdec + 8); q2f4(us[3], sdec + 12);
    const u32x4* xp = reinterpret_cast<const u32x4*>(xfc + (size_t)node * 128 + c0);
    u32x4 x0 = xp[0], x1 = xp[1];
    uint xw[8] = {x0[0], x0[1], x0[2], x0[3], x1[0], x1[1], x1[2], x1[3]};
    float bb[16];
#pragma unroll
    for (int p = 0; p < 4; ++p) {
        float4 bq = *reinterpret_cast<const float4*>(b1 + c0 + p * 4);
        bb[4 * p] = bq.x; bb[4 * p + 1] = bq.y; bb[4 * p + 2] = bq.z; bb[4 * p + 3] = bq.w;
    }
    uint outw[8];
#pragma unroll
    for (int jj = 0; jj < 8; ++jj) {
        int e0 = 2 * jj, e1 = 2 * jj + 1;
        float v0 = fmaxf((acc[e0] + sdec[e0]) * di + bb[e0], 0.f) + bf2f((ushort)(xw[jj] & 0xffff));
        float v1 = fmaxf((acc[e1] + sdec[e1]) * di + bb[e1], 0.f) + bf2f((ushort)(xw[jj] >> 16));
        outw[jj] = (uint)f2bf(v0) | ((uint)f2bf(v1) << 16);
    }
    ushort* hp = h + (size_t)node * 128 + c0;
    u32x4 o0 = {outw[0], outw[1], outw[2], outw[3]};
    u32x4 o1 = {outw[4], outw[5], outw[6], outw[7]};
    *reinterpret_cast<u32x4*>(hp) = o0;
    *reinterpret_cast<u32x4*>(hp + 8) = o1;
}

// ---------------- aggregation 2 + residual + pool (no per-node output) ----------------
// pool_c += relu(dinv_i*(sum h2q[s] + h2q[i]) + b2)_c + h_i_c

__global__ __launch_bounds__(256) void k_agg2(
    const int* __restrict__ csr, const int* __restrict__ offs, const int* __restrict__ degE,
    const float* __restrict__ dinv, const uchar* __restrict__ h2q, const ushort* __restrict__ hres,
    const float* __restrict__ b2, float* __restrict__ pooled, int n)
{
    __shared__ float lpool[128];
    int t = threadIdx.x;
    if (t < 128) lpool[t] = 0.f;
    __syncthreads();
    int g = t >> 3, li = t & 7;
    int node = blockIdx.x * 32 + g;
    bool valid = node < n;
    int nodeC = valid ? node : (n - 1);
    int off = offs[nodeC];
    int cnt = valid ? degE[nodeC] : 0;
    float di = dinv[nodeC];
    int c0 = li * 16;
    const uchar* tbl = h2q + c0;
    float acc[16];
#pragma unroll
    for (int e = 0; e < 16; ++e) acc[e] = 0.f;

    for (int base = 0; base < cnt; base += 8) {
        u32x4 u[8];
#pragma unroll
        for (int q = 0; q < 8; ++q) {
            int s = csr[off + base + q];
            int id = (base + q < cnt) ? s : n;
            u[q] = *reinterpret_cast<const u32x4*>(tbl + (size_t)id * 128);
        }
#pragma unroll
        for (int q = 0; q < 8; ++q) {
            float d4[4];
            q2f4(u[q][0], d4); acc[0] += d4[0]; acc[1] += d4[1]; acc[2] += d4[2]; acc[3] += d4[3];
            q2f4(u[q][1], d4); acc[4] += d4[0]; acc[5] += d4[1]; acc[6] += d4[2]; acc[7] += d4[3];
            q2f4(u[q][2], d4); acc[8] += d4[0]; acc[9] += d4[1]; acc[10] += d4[2]; acc[11] += d4[3];
            q2f4(u[q][3], d4); acc[12] += d4[0]; acc[13] += d4[1]; acc[14] += d4[2]; acc[15] += d4[3];
        }
    }

    u32x4 us = *reinterpret_cast<const u32x4*>(tbl + (size_t)nodeC * 128);
    float sdec[16];
    q2f4(us[0], sdec); q2f4(us[1], sdec + 4); q2f4(us[2], sdec + 8); q2f4(us[3], sdec + 12);
    const u32x4* rp = reinterpret_cast<const u32x4*>(hres + (size_t)nodeC * 128 + c0);
    u32x4 r0 = rp[0], r1 = rp[1];
    uint rw[8] = {r0[0], r0[1], r0[2], r0[3], r1[0], r1[1], r1[2], r1[3]};
    float bb[16];
#pragma unroll
    for (int p = 0; p < 4; ++p) {
        float4 bq = *reinterpret_cast<const float4*>(b2 + c0 + p * 4);
        bb[4 * p] = bq.x; bb[4 * p + 1] = bq.y; bb[4 * p + 2] = bq.z; bb[4 * p + 3] = bq.w;
    }
    if (valid) {
#pragma unroll
        for (int jj = 0; jj < 8; ++jj) {
            int e0 = 2 * jj, e1 = 2 * jj + 1;
            float v0 = fmaxf((acc[e0] + sdec[e0]) * di + bb[e0], 0.f) + bf2f((ushort)(rw[jj] & 0xffff));
            float v1 = fmaxf((acc[e1] + sdec[e1]) * di + bb[e1], 0.f) + bf2f((ushort)(rw[jj] >> 16));
            atomicAdd(&lpool[c0 + e0], v0);
            atomicAdd(&lpool[c0 + e1], v1);
        }
    }
    __syncthreads();
    if (t < 128) atomicAdd(&pooled[t], lpool[t]);
}

// ---------------- final: sigmoid(mean @ Wfc + bfc) ----------------

__global__ void k_final(const float* __restrict__ pooled, const float* __restrict__ Wfc,
                        const float* __restrict__ bfc, float* __restrict__ out, float invN) {
    int lane = threadIdx.x;
    float s = pooled[2 * lane] * invN * Wfc[2 * lane] +
              pooled[2 * lane + 1] * invN * Wfc[2 * lane + 1];
#pragma unroll
    for (int off = 32; off > 0; off >>= 1) s += __shfl_down(s, off);
    if (lane == 0) out[0] = 1.f / (1.f + expf(-(s + bfc[0])));
}

// ---------------- launch ----------------

extern "C" void kernel_launch(void* const* d_in, const int* in_sizes, int n_in,
                              void* d_out, int out_size, void* d_ws, size_t ws_size,
                              hipStream_t stream) {
    const float* x   = (const float*)d_in[0];
    const int*   ei  = (const int*)d_in[1];
    const float* W1  = (const float*)d_in[2];
    const float* b1  = (const float*)d_in[3];
    const float* W2  = (const float*)d_in[4];
    const float* b2  = (const float*)d_in[5];
    const float* We  = (const float*)d_in[6];
    const float* be  = (const float*)d_in[7];
    const float* Wfc = (const float*)d_in[8];
    const float* bfc = (const float*)d_in[9];
    float* out = (float*)d_out;

    const int N = in_sizes[0] / 128;
    const int E = in_sizes[1] / 2;
    const int* src = ei;
    const int* dst = ei + E;

    char* w = (char*)d_ws;
    size_t off = 0;
    auto take = [&](size_t bytes) -> void* {
        void* p = w + off;
        off = (off + bytes + 255) & ~(size_t)255;
        return p;
    };
    int*    deg    = (int*)take((size_t)N * 4);
    int*    offs   = (int*)take((size_t)N * 4);
    int*    cursor = (int*)take((size_t)N * 4);
    float*  dinv   = (float*)take((size_t)N * 4);
    int*    bsum   = (int*)take(1024);
    int*    boff   = (int*)take(1024);
    float*  pooled = (float*)take(512);
    int*    csr    = (int*)take((size_t)(E + 64) * 4);
    uchar*  h1q    = (uchar*)take((size_t)(N + 1) * 128);      // row N = zeros
    ushort* xfc    = (ushort*)take((size_t)N * 128 * 2);
    ushort* h      = (ushort*)take((size_t)N * 128 * 2);
    uchar*  h2q    = (uchar*)take((size_t)(N + 1) * 128);      // row N = zeros

    const int nbScan = (N + 1023) / 1024;
    const int nbN = (N + 255) / 256;

    k_init<<<nbN, 256, 0, stream>>>(deg, cursor, pooled,
                                    h1q + (size_t)N * 128, h2q + (size_t)N * 128, N);
    k_degree<<<2048, 256, 0, stream>>>(dst, deg, E, N);
    k_dinv<<<nbN, 256, 0, stream>>>(deg, dinv, N);
    k_scan_a<<<nbScan, 256, 0, stream>>>(deg, bsum, N);
    k_scan_b<<<1, 256, 0, stream>>>(bsum, boff, nbScan);
    k_scan_c<<<nbScan, 256, 0, stream>>>(deg, boff, offs, N);
    k_fill<<<2048, 256, 0, stream>>>(src, dst, offs, cursor, csr, E, N);

    k_gemm1<<<(N + 127) / 128, 512, 0, stream>>>(x, W1, We, be, dinv, h1q, xfc, N);
    k_agg1<<<(N + 31) / 32, 256, 0, stream>>>(csr, offs, deg, dinv, h1q, xfc, b1, h, N);
    k_gemm2<<<(N + 127) / 128, 512, 0, stream>>>(h, W2, dinv, h2q, N);
    k_agg2<<<(N + 31) / 32, 256, 0, stream>>>(csr, offs, deg, dinv, h2q, h, b2, pooled, N);
    k_final<<<1, 64, 0, stream>>>(pooled, Wfc, bfc, out, 1.0f / (float)N);
}

// Round 16
// 375.456 us; speedup vs baseline: 2.4692x; 1.0558x over previous
//
#include <hip/hip_runtime.h>
#include <hip/hip_bf16.h>

typedef unsigned int uint;
typedef unsigned short ushort;
typedef unsigned char uchar;
typedef __attribute__((ext_vector_type(8))) short short8;
typedef __attribute__((ext_vector_type(4))) float f32x4;
typedef __attribute__((ext_vector_type(4))) uint u32x4;

__device__ __forceinline__ float bf2f(ushort u) {
    union { uint i; float f; } v; v.i = ((uint)u) << 16; return v.f;
}
__device__ __forceinline__ ushort f2bf(float f) {
    union { float f; uint i; } v; v.f = f;
    uint x = v.i;
    uint r = (x + 0x7FFFu + ((x >> 16) & 1u)) >> 16;
    return (ushort)r;
}
// fp8 e4m3 encode via HW cvt
__device__ __forceinline__ uchar f2q(float f) {
    return (uchar)(__builtin_amdgcn_cvt_pk_fp8_f32(f, 0.f, 0, false) & 0xFF);
}
// decode 4 fp8 from a word (literal selectors required)
__device__ __forceinline__ void q2f4(uint w, float* o) {
    o[0] = __builtin_amdgcn_cvt_f32_fp8(w, 0);
    o[1] = __builtin_amdgcn_cvt_f32_fp8(w, 1);
    o[2] = __builtin_amdgcn_cvt_f32_fp8(w, 2);
    o[3] = __builtin_amdgcn_cvt_f32_fp8(w, 3);
}

// ---------------- init: all zeroing in one launch ----------------

__global__ void k_init(int* __restrict__ deg, int* __restrict__ cursor,
                       float* __restrict__ pooled,
                       uchar* __restrict__ h1qN, uchar* __restrict__ h2qN, int n) {
    int i = blockIdx.x * 256 + threadIdx.x;
    if (i < n) { deg[i] = 0; cursor[i] = 0; }
    if (i < 128) pooled[i] = 0.f;
    if (i < 32) {
        reinterpret_cast<uint*>(h1qN)[i] = 0;      // zero row N of fp8 tables
        reinterpret_cast<uint*>(h2qN)[i] = 0;
    }
}

// ---------------- graph prep ----------------
// Binned by dst range (bin = blockIdx & 7): each 64B line of deg/cursor/csr
// is written by one XCD only -> no cross-XCD partial-line writeback (R5 fix).

__global__ void k_degree(const int* __restrict__ dst, int* __restrict__ deg,
                         int e, int n) {
    int bin = blockIdx.x & 7;
    int sub = blockIdx.x >> 3;
    int nsub = gridDim.x >> 3;
    int q = (n + 7) >> 3;
    int lo = bin * q, hi = min(n, lo + q);
    for (int i = sub * 256 + threadIdx.x; i < e; i += nsub * 256) {
        int d = dst[i];
        if (d >= lo && d < hi) atomicAdd(&deg[d], 1);
    }
}

__global__ void k_dinv(const int* __restrict__ deg, float* __restrict__ dinv, int n) {
    int i = blockIdx.x * 256 + threadIdx.x;
    if (i < n) dinv[i] = rsqrtf((float)deg[i] + 1.0f);  // +1 self-loop
}

// 3-kernel exclusive scan of edge-degree -> offsets. chunk = 1024/block.
__global__ void k_scan_a(const int* __restrict__ deg, int* __restrict__ bsum, int n) {
    __shared__ int sd[256];
    int t = threadIdx.x;
    int base = blockIdx.x * 1024 + t * 4;
    int s = 0;
#pragma unroll
    for (int j = 0; j < 4; ++j) { int idx = base + j; if (idx < n) s += deg[idx]; }
    sd[t] = s; __syncthreads();
    for (int off = 1; off < 256; off <<= 1) {
        int v = (t >= off) ? sd[t - off] : 0;
        __syncthreads();
        sd[t] += v;
        __syncthreads();
    }
    if (t == 255) bsum[blockIdx.x] = sd[255];
}

__global__ void k_scan_b(const int* __restrict__ bsum, int* __restrict__ boff, int nb) {
    __shared__ int sd[256];
    int t = threadIdx.x;
    int v0 = (t < nb) ? bsum[t] : 0;
    sd[t] = v0; __syncthreads();
    for (int off = 1; off < 256; off <<= 1) {
        int v = (t >= off) ? sd[t - off] : 0;
        __syncthreads();
        sd[t] += v;
        __syncthreads();
    }
    if (t < nb) boff[t] = sd[t] - v0;  // exclusive
}

__global__ void k_scan_c(const int* __restrict__ deg, const int* __restrict__ boff,
                         int* __restrict__ offs, int n) {
    __shared__ int sd[256];
    int t = threadIdx.x;
    int base = blockIdx.x * 1024 + t * 4;
    int vals[4]; int s = 0;
#pragma unroll
    for (int j = 0; j < 4; ++j) {
        int idx = base + j;
        vals[j] = (idx < n) ? deg[idx] : 0;
        s += vals[j];
    }
    sd[t] = s; __syncthreads();
    for (int off = 1; off < 256; off <<= 1) {
        int v = (t >= off) ? sd[t - off] : 0;
        __syncthreads();
        sd[t] += v;
        __syncthreads();
    }
    int run = boff[blockIdx.x] + (sd[t] - s);
#pragma unroll
    for (int j = 0; j < 4; ++j) {
        int idx = base + j;
        if (idx < n) { offs[idx] = run; run += vals[j]; }
    }
}

__global__ void k_fill(const int* __restrict__ src, const int* __restrict__ dst,
                       const int* __restrict__ offs, int* __restrict__ cursor,
                       int* __restrict__ csr, int e, int n) {
    int bin = blockIdx.x & 7;
    int sub = blockIdx.x >> 3;
    int nsub = gridDim.x >> 3;
    int q = (n + 7) >> 3;
    int lo = bin * q, hi = min(n, lo + q);
    for (int i = sub * 256 + threadIdx.x; i < e; i += nsub * 256) {
        int d = dst[i];
        if (d >= lo && d < hi) {
            int p = offs[d] + atomicAdd(&cursor[d], 1);
            csr[p] = src[i];
        }
    }
}

// ---------------- GEMM1: h1q = fp8((x@W1)*dinv), xfc = bf16(relu(x@We+be)) ----------------

__global__ __launch_bounds__(512) void k_gemm1(
    const float* __restrict__ x, const float* __restrict__ W1, const float* __restrict__ We,
    const float* __restrict__ be, const float* __restrict__ dinv,
    uchar* __restrict__ h1q, ushort* __restrict__ xfc, int n)
{
    __shared__ __align__(16) ushort Bt[256][72];  // [col][k_local], pad 72 for banks
    int tid = threadIdx.x;
    int w = tid >> 6, lane = tid & 63;
    int ln15 = lane & 15, g = lane >> 4;
    int rowBase = blockIdx.x * 128 + w * 16;
    int r = rowBase + ln15;
    bool valid = r < n;

    short8 a[4];
#pragma unroll
    for (int ks = 0; ks < 4; ++ks) {
        float4 f0 = make_float4(0.f, 0.f, 0.f, 0.f), f1 = f0;
        if (valid) {
            const float* p = x + (size_t)r * 128 + ks * 32 + g * 8;
            f0 = *reinterpret_cast<const float4*>(p);
            f1 = *reinterpret_cast<const float4*>(p + 4);
        }
        short8 v;
        v[0] = (short)f2bf(f0.x); v[1] = (short)f2bf(f0.y);
        v[2] = (short)f2bf(f0.z); v[3] = (short)f2bf(f0.w);
        v[4] = (short)f2bf(f1.x); v[5] = (short)f2bf(f1.y);
        v[6] = (short)f2bf(f1.z); v[7] = (short)f2bf(f1.w);
        a[ks] = v;
    }

    f32x4 acc[16];
#pragma unroll
    for (int i = 0; i < 16; ++i) acc[i] = (f32x4){0.f, 0.f, 0.f, 0.f};

    for (int s = 0; s < 2; ++s) {
        for (int i = tid; i < 8192; i += 512) {
            int kl = i >> 7, j = i & 127;
            int kg = s * 64 + kl;
            Bt[j][kl]       = f2bf(W1[kg * 128 + j]);
            Bt[128 + j][kl] = f2bf(We[kg * 128 + j]);
        }
        __syncthreads();
#pragma unroll
        for (int t2 = 0; t2 < 2; ++t2) {
            short8 af = a[s * 2 + t2];
#pragma unroll
            for (int jf = 0; jf < 16; ++jf) {
                short8 bf = *reinterpret_cast<const short8*>(&Bt[jf * 16 + ln15][t2 * 32 + g * 8]);
                acc[jf] = __builtin_amdgcn_mfma_f32_16x16x32_bf16(af, bf, acc[jf], 0, 0, 0);
            }
        }
        __syncthreads();
    }

    float dv[4];
#pragma unroll
    for (int q = 0; q < 4; ++q) {
        int rr = rowBase + g * 4 + q;
        dv[q] = (rr < n) ? dinv[rr] : 0.f;
    }

    // D layout: col = lane&15, row = (lane>>4)*4 + q
#pragma unroll
    for (int jf = 0; jf < 16; ++jf) {
        int col = jf * 16 + ln15;
#pragma unroll
        for (int q = 0; q < 4; ++q) {
            int rr = rowBase + g * 4 + q;
            if (rr < n) {
                float v = acc[jf][q];
                if (col < 128) {
                    h1q[(size_t)rr * 128 + col] = f2q(v * dv[q]);
                } else {
                    float vv = fmaxf(v + be[col - 128], 0.f);
                    xfc[(size_t)rr * 128 + (col - 128)] = f2bf(vv);
                }
            }
        }
    }
}

// ---------------- GEMM2: h2q = fp8((h@W2)*dinv) (bf16 in) ----------------

__global__ __launch_bounds__(512) void k_gemm2(
    const ushort* __restrict__ h, const float* __restrict__ W2, const float* __restrict__ dinv,
    uchar* __restrict__ h2q, int n)
{
    __shared__ __align__(16) ushort Bt[128][72];
    int tid = threadIdx.x;
    int w = tid >> 6, lane = tid & 63;
    int ln15 = lane & 15, g = lane >> 4;
    int rowBase = blockIdx.x * 128 + w * 16;
    int r = rowBase + ln15;
    bool valid = r < n;

    short8 a[4];
#pragma unroll
    for (int ks = 0; ks < 4; ++ks) {
        short8 v = (short8){0,0,0,0,0,0,0,0};
        if (valid) v = *reinterpret_cast<const short8*>(h + (size_t)r * 128 + ks * 32 + g * 8);
        a[ks] = v;
    }

    f32x4 acc[8];
#pragma unroll
    for (int i = 0; i < 8; ++i) acc[i] = (f32x4){0.f, 0.f, 0.f, 0.f};

    for (int s = 0; s < 2; ++s) {
        for (int i = tid; i < 8192; i += 512) {
            int kl = i >> 7, j = i & 127;
            Bt[j][kl] = f2bf(W2[(s * 64 + kl) * 128 + j]);
        }
        __syncthreads();
#pragma unroll
        for (int t2 = 0; t2 < 2; ++t2) {
            short8 af = a[s * 2 + t2];
#pragma unroll
            for (int jf = 0; jf < 8; ++jf) {
                short8 bf = *reinterpret_cast<const short8*>(&Bt[jf * 16 + ln15][t2 * 32 + g * 8]);
                acc[jf] = __builtin_amdgcn_mfma_f32_16x16x32_bf16(af, bf, acc[jf], 0, 0, 0);
            }
        }
        __syncthreads();
    }

    float dv[4];
#pragma unroll
    for (int q = 0; q < 4; ++q) {
        int rr = rowBase + g * 4 + q;
        dv[q] = (rr < n) ? dinv[rr] : 0.f;
    }

#pragma unroll
    for (int jf = 0; jf < 8; ++jf) {
        int col = jf * 16 + ln15;
#pragma unroll
        for (int q = 0; q < 4; ++q) {
            int rr = rowBase + g * 4 + q;
            if (rr < n) h2q[(size_t)rr * 128 + col] = f2q(acc[jf][q] * dv[q]);
        }
    }
}

// ---------------- aggregation 1 ----------------
// h_i = relu(dinv_i*(sum_{s in N(i)} h1q[s] + h1q[i]) + b1) + xfc_i   (bf16 out)
// 8-lane group per node; lane owns 16 channels (16B fp8 gathers; group's 8
// lanes cover the 128B row in one instruction). Per 8-edge batch: ONE
// coalesced csr load (lane li -> idx of edge base+li) + 8 __shfl broadcasts
// (DS pipe) + 8 gathers. VMEM instrs/batch: 16 -> 9. (R15 model: aggs are
// VMEM-instruction/TA bound at ~70cyc fixed + ~4cyc/line per instruction;
// the 8 redundant per-lane csr loads were half the instruction stream.)
// Tail edges clamp to zero-row n. csr padded +64.

__global__ __launch_bounds__(256) void k_agg1(
    const int* __restrict__ csr, const int* __restrict__ offs, const int* __restrict__ degE,
    const float* __restrict__ dinv, const uchar* __restrict__ h1q, const ushort* __restrict__ xfc,
    const float* __restrict__ b1, ushort* __restrict__ h, int n)
{
    int t = threadIdx.x;
    int g = t >> 3, li = t & 7;
    int lane = t & 63, gb = lane & 56;         // group base lane within wave
    int node = blockIdx.x * 32 + g;
    if (node >= n) return;
    int off = offs[node], cnt = degE[node];
    float di = dinv[node];
    int c0 = li * 16;
    const uchar* tbl = h1q + c0;
    float acc[16];
#pragma unroll
    for (int e = 0; e < 16; ++e) acc[e] = 0.f;

    for (int base = 0; base < cnt; base += 8) {
        int k = base + li;
        int s = csr[off + k];                  // 1 coalesced dword / group
        int myidx = (k < cnt) ? s : n;         // zero row for tail
        u32x4 u[8];
#pragma unroll
        for (int q = 0; q < 8; ++q) {
            int sj = __shfl(myidx, gb + q);    // broadcast edge q's index
            u[q] = *reinterpret_cast<const u32x4*>(tbl + (size_t)sj * 128);
        }
#pragma unroll
        for (int q = 0; q < 8; ++q) {
            float d4[4];
            q2f4(u[q][0], d4); acc[0] += d4[0]; acc[1] += d4[1]; acc[2] += d4[2]; acc[3] += d4[3];
            q2f4(u[q][1], d4); acc[4] += d4[0]; acc[5] += d4[1]; acc[6] += d4[2]; acc[7] += d4[3];
            q2f4(u[q][2], d4); acc[8] += d4[0]; acc[9] += d4[1]; acc[10] += d4[2]; acc[11] += d4[3];
            q2f4(u[q][3], d4); acc[12] += d4[0]; acc[13] += d4[1]; acc[14] += d4[2]; acc[15] += d4[3];
        }
    }

    u32x4 us = *reinterpret_cast<const u32x4*>(tbl + (size_t)node * 128);
    float sdec[16];
    q2f4(us[0], sdec); q2f4(us[1], sdec + 4); q2f4(us[2], sdec + 8); q2f4(us[3], sdec + 12);
    const u32x4* xp = reinterpret_cast<const u32x4*>(xfc + (size_t)node * 128 + c0);
    u32x4 x0 = xp[0], x1 = xp[1];
    uint xw[8] = {x0[0], x0[1], x0[2], x0[3], x1[0], x1[1], x1[2], x1[3]};
    float bb[16];
#pragma unroll
    for (int p = 0; p < 4; ++p) {
        float4 bq = *reinterpret_cast<const float4*>(b1 + c0 + p * 4);
        bb[4 * p] = bq.x; bb[4 * p + 1] = bq.y; bb[4 * p + 2] = bq.z; bb[4 * p + 3] = bq.w;
    }
    uint outw[8];
#pragma unroll
    for (int jj = 0; jj < 8; ++jj) {
        int e0 = 2 * jj, e1 = 2 * jj + 1;
        float v0 = fmaxf((acc[e0] + sdec[e0]) * di + bb[e0], 0.f) + bf2f((ushort)(xw[jj] & 0xffff));
        float v1 = fmaxf((acc[e1] + sdec[e1]) * di + bb[e1], 0.f) + bf2f((ushort)(xw[jj] >> 16));
        outw[jj] = (uint)f2bf(v0) | ((uint)f2bf(v1) << 16);
    }
    ushort* hp = h + (size_t)node * 128 + c0;
    u32x4 o0 = {outw[0], outw[1], outw[2], outw[3]};
    u32x4 o1 = {outw[4], outw[5], outw[6], outw[7]};
    *reinterpret_cast<u32x4*>(hp) = o0;
    *reinterpret_cast<u32x4*>(hp + 8) = o1;
}

// ---------------- aggregation 2 + residual + pool (no per-node output) ----------------
// pool_c += relu(dinv_i*(sum h2q[s] + h2q[i]) + b2)_c + h_i_c

__global__ __launch_bounds__(256) void k_agg2(
    const int* __restrict__ csr, const int* __restrict__ offs, const int* __restrict__ degE,
    const float* __restrict__ dinv, const uchar* __restrict__ h2q, const ushort* __restrict__ hres,
    const float* __restrict__ b2, float* __restrict__ pooled, int n)
{
    __shared__ float lpool[128];
    int t = threadIdx.x;
    if (t < 128) lpool[t] = 0.f;
    __syncthreads();
    int g = t >> 3, li = t & 7;
    int lane = t & 63, gb = lane & 56;
    int node = blockIdx.x * 32 + g;
    bool valid = node < n;
    int nodeC = valid ? node : (n - 1);
    int off = offs[nodeC];
    int cnt = valid ? degE[nodeC] : 0;
    float di = dinv[nodeC];
    int c0 = li * 16;
    const uchar* tbl = h2q + c0;
    float acc[16];
#pragma unroll
    for (int e = 0; e < 16; ++e) acc[e] = 0.f;

    for (int base = 0; base < cnt; base += 8) {
        int k = base + li;
        int s = csr[off + k];
        int myidx = (k < cnt) ? s : n;
        u32x4 u[8];
#pragma unroll
        for (int q = 0; q < 8; ++q) {
            int sj = __shfl(myidx, gb + q);
            u[q] = *reinterpret_cast<const u32x4*>(tbl + (size_t)sj * 128);
        }
#pragma unroll
        for (int q = 0; q < 8; ++q) {
            float d4[4];
            q2f4(u[q][0], d4); acc[0] += d4[0]; acc[1] += d4[1]; acc[2] += d4[2]; acc[3] += d4[3];
            q2f4(u[q][1], d4); acc[4] += d4[0]; acc[5] += d4[1]; acc[6] += d4[2]; acc[7] += d4[3];
            q2f4(u[q][2], d4); acc[8] += d4[0]; acc[9] += d4[1]; acc[10] += d4[2]; acc[11] += d4[3];
            q2f4(u[q][3], d4); acc[12] += d4[0]; acc[13] += d4[1]; acc[14] += d4[2]; acc[15] += d4[3];
        }
    }

    u32x4 us = *reinterpret_cast<const u32x4*>(tbl + (size_t)nodeC * 128);
    float sdec[16];
    q2f4(us[0], sdec); q2f4(us[1], sdec + 4); q2f4(us[2], sdec + 8); q2f4(us[3], sdec + 12);
    const u32x4* rp = reinterpret_cast<const u32x4*>(hres + (size_t)nodeC * 128 + c0);
    u32x4 r0 = rp[0], r1 = rp[1];
    uint rw[8] = {r0[0], r0[1], r0[2], r0[3], r1[0], r1[1], r1[2], r1[3]};
    float bb[16];
#pragma unroll
    for (int p = 0; p < 4; ++p) {
        float4 bq = *reinterpret_cast<const float4*>(b2 + c0 + p * 4);
        bb[4 * p] = bq.x; bb[4 * p + 1] = bq.y; bb[4 * p + 2] = bq.z; bb[4 * p + 3] = bq.w;
    }
    if (valid) {
#pragma unroll
        for (int jj = 0; jj < 8; ++jj) {
            int e0 = 2 * jj, e1 = 2 * jj + 1;
            float v0 = fmaxf((acc[e0] + sdec[e0]) * di + bb[e0], 0.f) + bf2f((ushort)(rw[jj] & 0xffff));
            float v1 = fmaxf((acc[e1] + sdec[e1]) * di + bb[e1], 0.f) + bf2f((ushort)(rw[jj] >> 16));
            atomicAdd(&lpool[c0 + e0], v0);
            atomicAdd(&lpool[c0 + e1], v1);
        }
    }
    __syncthreads();
    if (t < 128) atomicAdd(&pooled[t], lpool[t]);
}

// ---------------- final: sigmoid(mean @ Wfc + bfc) ----------------

__global__ void k_final(const float* __restrict__ pooled, const float* __restrict__ Wfc,
                        const float* __restrict__ bfc, float* __restrict__ out, float invN) {
    int lane = threadIdx.x;
    float s = pooled[2 * lane] * invN * Wfc[2 * lane] +
              pooled[2 * lane + 1] * invN * Wfc[2 * lane + 1];
#pragma unroll
    for (int off = 32; off > 0; off >>= 1) s += __shfl_down(s, off);
    if (lane == 0) out[0] = 1.f / (1.f + expf(-(s + bfc[0])));
}

// ---------------- launch ----------------

extern "C" void kernel_launch(void* const* d_in, const int* in_sizes, int n_in,
                              void* d_out, int out_size, void* d_ws, size_t ws_size,
                              hipStream_t stream) {
    const float* x   = (const float*)d_in[0];
    const int*   ei  = (const int*)d_in[1];
    const float* W1  = (const float*)d_in[2];
    const float* b1  = (const float*)d_in[3];
    const float* W2  = (const float*)d_in[4];
    const float* b2  = (const float*)d_in[5];
    const float* We  = (const float*)d_in[6];
    const float* be  = (const float*)d_in[7];
    const float* Wfc = (const float*)d_in[8];
    const float* bfc = (const float*)d_in[9];
    float* out = (float*)d_out;

    const int N = in_sizes[0] / 128;
    const int E = in_sizes[1] / 2;
    const int* src = ei;
    const int* dst = ei + E;

    char* w = (char*)d_ws;
    size_t off = 0;
    auto take = [&](size_t bytes) -> void* {
        void* p = w + off;
        off = (off + bytes + 255) & ~(size_t)255;
        return p;
    };
    int*    deg    = (int*)take((size_t)N * 4);
    int*    offs   = (int*)take((size_t)N * 4);
    int*    cursor = (int*)take((size_t)N * 4);
    float*  dinv   = (float*)take((size_t)N * 4);
    int*    bsum   = (int*)take(1024);
    int*    boff   = (int*)take(1024);
    float*  pooled = (float*)take(512);
    int*    csr    = (int*)take((size_t)(E + 64) * 4);
    uchar*  h1q    = (uchar*)take((size_t)(N + 1) * 128);      // row N = zeros
    ushort* xfc    = (ushort*)take((size_t)N * 128 * 2);
    ushort* h      = (ushort*)take((size_t)N * 128 * 2);
    uchar*  h2q    = (uchar*)take((size_t)(N + 1) * 128);      // row N = zeros

    const int nbScan = (N + 1023) / 1024;
    const int nbN = (N + 255) / 256;

    k_init<<<nbN, 256, 0, stream>>>(deg, cursor, pooled,
                                    h1q + (size_t)N * 128, h2q + (size_t)N * 128, N);
    k_degree<<<2048, 256, 0, stream>>>(dst, deg, E, N);
    k_dinv<<<nbN, 256, 0, stream>>>(deg, dinv, N);
    k_scan_a<<<nbScan, 256, 0, stream>>>(deg, bsum, N);
    k_scan_b<<<1, 256, 0, stream>>>(bsum, boff, nbScan);
    k_scan_c<<<nbScan, 256, 0, stream>>>(deg, boff, offs, N);
    k_fill<<<2048, 256, 0, stream>>>(src, dst, offs, cursor, csr, E, N);

    k_gemm1<<<(N + 127) / 128, 512, 0, stream>>>(x, W1, We, be, dinv, h1q, xfc, N);
    k_agg1<<<(N + 31) / 32, 256, 0, stream>>>(csr, offs, deg, dinv, h1q, xfc, b1, h, N);
    k_gemm2<<<(N + 127) / 128, 512, 0, stream>>>(h, W2, dinv, h2q, N);
    k_agg2<<<(N + 31) / 32, 256, 0, stream>>>(csr, offs, deg, dinv, h2q, h, b2, pooled, N);
    k_final<<<1, 64, 0, stream>>>(pooled, Wfc, bfc, out, 1.0f / (float)N);
}